// Round 6
// baseline (821.747 us; speedup 1.0000x reference)
//
#include <hip/hip_runtime.h>

#define N_NODES 50000
#define N_EDGES 800000
#define IN_F    256
#define HIDDEN  128

#define BUCKET_SZ 64                      // rows per bucket
#define NB        782                     // ceil(N_NODES / 64)
#define NBP       1024                    // padded scan width (4 per thread x 256)
#define EBLOCK    2048                    // edges per partition block
#define EBLOCKS   391                     // ceil(N_EDGES / EBLOCK)
#define CAP       1344                    // bucket region capacity (mean 1023, +10 sigma)
#define OV_CAP    4096                    // overflow list capacity

typedef __attribute__((ext_vector_type(8))) short bf16x8;
typedef __attribute__((ext_vector_type(4))) float f32x4;

__device__ inline unsigned short f2bf(float f) {
    unsigned u = __float_as_uint(f);
    u += 0x7FFF + ((u >> 16) & 1);          // round-to-nearest-even
    return (unsigned short)(u >> 16);
}
__device__ inline bf16x8 cvt8(float4 a, float4 b) {
    bf16x8 r;
    r[0] = (short)f2bf(a.x); r[1] = (short)f2bf(a.y);
    r[2] = (short)f2bf(a.z); r[3] = (short)f2bf(a.w);
    r[4] = (short)f2bf(b.x); r[5] = (short)f2bf(b.y);
    r[6] = (short)f2bf(b.z); r[7] = (short)f2bf(b.w);
    return r;
}
__device__ inline float bfLo(unsigned u) { return __uint_as_float(u << 16); }
__device__ inline float bfHi(unsigned u) { return __uint_as_float(u & 0xFFFF0000u); }

// ---------------------------------------------------------------------------
// Linear via MFMA bf16 (verified R4/R5): W staged once per block in LDS,
// pre-swizzled into B-fragment order; A-frags via coalesced global loads.
// ---------------------------------------------------------------------------
__global__ __launch_bounds__(256) void linear_mfma_kernel(
    const float* __restrict__ x, const float* __restrict__ W,
    const float* __restrict__ bias, unsigned short* __restrict__ support)
{
    __shared__ __align__(16) short wfrag[8 * 8 * 64 * 8];   // 64 KB

    const int tid = threadIdx.x;
#pragma unroll
    for (int it = 0; it < 16; ++it) {
        const int f    = it * 256 + tid;
        const int ln   = f & 63;
        const int s    = (f >> 6) & 7;
        const int kc   = f >> 9;
        const int row  = s * 16 + (ln & 15);
        const int k0   = kc * 32 + (ln >> 4) * 8;
        const float* wp = W + (size_t)row * IN_F + k0;
        float4 b0 = *(const float4*)wp;
        float4 b1 = *(const float4*)(wp + 4);
        *(bf16x8*)(&wfrag[(size_t)f * 8]) = cvt8(b0, b1);
    }
    __syncthreads();

    const int lane = tid & 63;
    const int wave = tid >> 6;
    const int quad = lane >> 4;
    const int l16  = lane & 15;

    int m = blockIdx.x * 64 + wave * 16 + l16;
    if (m >= N_NODES) m = N_NODES - 1;
    const float* xrow = x + (size_t)m * IN_F;

    f32x4 acc[8];
#pragma unroll
    for (int s = 0; s < 8; ++s) acc[s] = (f32x4){0.f, 0.f, 0.f, 0.f};

#pragma unroll
    for (int kc = 0; kc < 8; ++kc) {
        const int k0 = kc * 32 + quad * 8;
        float4 a0 = *(const float4*)(xrow + k0);
        float4 a1 = *(const float4*)(xrow + k0 + 4);
        bf16x8 af = cvt8(a0, a1);
        const short* bbase = &wfrag[((size_t)(kc * 8) * 64 + lane) * 8];
#pragma unroll
        for (int s = 0; s < 8; ++s) {
            bf16x8 bf = *(const bf16x8*)(bbase + (size_t)s * 64 * 8);
            acc[s] = __builtin_amdgcn_mfma_f32_16x16x32_bf16(af, bf, acc[s], 0, 0, 0);
        }
    }

    const int rowBase = blockIdx.x * 64 + wave * 16 + quad * 4;
#pragma unroll
    for (int reg = 0; reg < 4; ++reg) {
        const int r = rowBase + reg;
        if (r < N_NODES) {
#pragma unroll
            for (int s = 0; s < 8; ++s) {
                const int col = s * 16 + l16;
                float v = acc[s][reg] + bias[col];
                support[(size_t)r * HIDDEN + col] = f2bf(v);
            }
        }
    }
}

// ---------------------------------------------------------------------------
// Partition: group each block's 2048 edges by bucket (row>>6) in LDS, reserve
// per-bucket space with ONE global atomicAdd per touched bucket, write
// bucket-contiguous runs into fixed-capacity regions part[b*CAP ..].
// Entry: .x = (bucket<<22)|(rowLocal<<16)|col   .y = val bits.
// ---------------------------------------------------------------------------
__global__ __launch_bounds__(256) void partition_kernel(
    const int* __restrict__ adj_row, const int* __restrict__ adj_col,
    const float* __restrict__ adj_val, int* __restrict__ cursor,
    int2* __restrict__ part, int4* __restrict__ ovbuf, int* __restrict__ ovcnt)
{
    __shared__ int  lcnt[NBP];     // counts, then exclusive offsets (lofs)
    __shared__ int  lcur[NBP];
    __shared__ int  gbase[NBP];
    __shared__ int  tsum[256];
    __shared__ int2 lbuf[EBLOCK];  // 16 KB

    const int tid  = threadIdx.x;
    const int base = blockIdx.x * EBLOCK;
    const int n    = min(EBLOCK, N_EDGES - base);

    for (int i = tid; i < NBP; i += 256) lcnt[i] = 0;
    __syncthreads();

    unsigned pk[8]; float pv[8];
#pragma unroll
    for (int i = 0; i < 8; ++i) {
        int e = base + tid + i * 256;
        bool ok = e < N_EDGES;
        int ee = ok ? e : 0;
        int r = adj_row[ee], c = adj_col[ee];
        float v = adj_val[ee];
        if (ok) {
            unsigned bk = (unsigned)r >> 6;
            pk[i] = (bk << 22) | (((unsigned)r & 63u) << 16) | (unsigned)c;
            pv[i] = v;
            atomicAdd(&lcnt[bk], 1);
        } else pk[i] = 0xFFFFFFFFu;
    }
    __syncthreads();

    // exclusive scan of lcnt[0..1024): 4 per thread + Hillis-Steele over 256
    int s0 = lcnt[tid * 4], s1 = lcnt[tid * 4 + 1];
    int s2 = lcnt[tid * 4 + 2], s3 = lcnt[tid * 4 + 3];
    int mysum = s0 + s1 + s2 + s3;
    tsum[tid] = mysum;
    __syncthreads();
#pragma unroll
    for (int off = 1; off < 256; off <<= 1) {
        int t = (tid >= off) ? tsum[tid - off] : 0;
        __syncthreads();
        tsum[tid] += t;
        __syncthreads();
    }
    int ex = tsum[tid] - mysum;
    lcnt[tid * 4]     = ex;
    lcnt[tid * 4 + 1] = ex + s0;
    lcnt[tid * 4 + 2] = ex + s0 + s1;
    lcnt[tid * 4 + 3] = ex + s0 + s1 + s2;
    __syncthreads();

    // reserve global space per touched bucket; init cursors
    for (int b = tid; b < NB; b += 256) {
        int c = lcnt[b + 1] - lcnt[b];
        gbase[b] = (c > 0) ? atomicAdd(&cursor[b], c) : 0;
        lcur[b]  = lcnt[b];
    }
    __syncthreads();

    // group into lbuf
#pragma unroll
    for (int i = 0; i < 8; ++i) {
        if (pk[i] != 0xFFFFFFFFu) {
            unsigned bk = pk[i] >> 22;
            int p = atomicAdd(&lcur[bk], 1);
            lbuf[p] = make_int2((int)pk[i], __float_as_int(pv[i]));
        }
    }
    __syncthreads();

    // write bucket-contiguous runs
    for (int j = tid; j < n; j += 256) {
        int2 cv = lbuf[j];
        unsigned bk = ((unsigned)cv.x) >> 22;
        int loc = gbase[bk] + (j - lcnt[bk]);
        if (loc < CAP) {
            part[(size_t)bk * CAP + loc] = make_int2(cv.x & 0x3FFFFF, cv.y);
        } else {
            int op = atomicAdd(ovcnt, 1);
            if (op < OV_CAP) {
                int r = (int)(bk * BUCKET_SZ) + ((cv.x >> 16) & 63);
                ovbuf[op] = make_int4(r, cv.x & 0xFFFF, cv.y, 0);
            }
        }
    }
}

// ---------------------------------------------------------------------------
// Bucket gather: block per bucket; LDS fp32 out-tile 64x128 (32 KB); per edge
// one coalesced 256 B support read + 2 ds_add_f32 per lane; float4 writeout.
// ---------------------------------------------------------------------------
__global__ __launch_bounds__(256) void bucket_gather_kernel(
    const int* __restrict__ cursor, const int2* __restrict__ part,
    const unsigned int* __restrict__ support_u32, float* __restrict__ out)
{
    __shared__ float tile[BUCKET_SZ * HIDDEN];   // 32 KB

    const int tid  = threadIdx.x;
    const int b    = blockIdx.x;
    const int n    = min(cursor[b], CAP);
    const int wave = tid >> 6;
    const int lane = tid & 63;

    for (int i = tid; i < BUCKET_SZ * HIDDEN; i += 256) tile[i] = 0.f;
    __syncthreads();

    const int2* pb = part + (size_t)b * CAP;
    int j = wave;
    for (; j + 12 < n; j += 16) {
        int2 cv0 = pb[j], cv1 = pb[j + 4], cv2 = pb[j + 8], cv3 = pb[j + 12];
        unsigned u0 = support_u32[(size_t)(cv0.x & 0xFFFF) * 64 + lane];
        unsigned u1 = support_u32[(size_t)(cv1.x & 0xFFFF) * 64 + lane];
        unsigned u2 = support_u32[(size_t)(cv2.x & 0xFFFF) * 64 + lane];
        unsigned u3 = support_u32[(size_t)(cv3.x & 0xFFFF) * 64 + lane];
        int r0 = (cv0.x >> 16) & 63, r1 = (cv1.x >> 16) & 63;
        int r2 = (cv2.x >> 16) & 63, r3 = (cv3.x >> 16) & 63;
        float v0 = __int_as_float(cv0.y), v1 = __int_as_float(cv1.y);
        float v2 = __int_as_float(cv2.y), v3 = __int_as_float(cv3.y);
        atomicAdd(&tile[r0 * HIDDEN + lane * 2    ], v0 * bfLo(u0));
        atomicAdd(&tile[r0 * HIDDEN + lane * 2 + 1], v0 * bfHi(u0));
        atomicAdd(&tile[r1 * HIDDEN + lane * 2    ], v1 * bfLo(u1));
        atomicAdd(&tile[r1 * HIDDEN + lane * 2 + 1], v1 * bfHi(u1));
        atomicAdd(&tile[r2 * HIDDEN + lane * 2    ], v2 * bfLo(u2));
        atomicAdd(&tile[r2 * HIDDEN + lane * 2 + 1], v2 * bfHi(u2));
        atomicAdd(&tile[r3 * HIDDEN + lane * 2    ], v3 * bfLo(u3));
        atomicAdd(&tile[r3 * HIDDEN + lane * 2 + 1], v3 * bfHi(u3));
    }
    for (; j < n; j += 4) {
        int2 cv = pb[j];
        unsigned u = support_u32[(size_t)(cv.x & 0xFFFF) * 64 + lane];
        int r = (cv.x >> 16) & 63;
        float v = __int_as_float(cv.y);
        atomicAdd(&tile[r * HIDDEN + lane * 2    ], v * bfLo(u));
        atomicAdd(&tile[r * HIDDEN + lane * 2 + 1], v * bfHi(u));
    }
    __syncthreads();

    const int rowsValid = min(BUCKET_SZ, N_NODES - b * BUCKET_SZ);
    for (int i = tid; i < rowsValid * (HIDDEN / 4); i += 256) {
        int r = i >> 5, q = i & 31;
        *(float4*)(out + ((size_t)(b * BUCKET_SZ + r)) * HIDDEN + q * 4) =
            *(float4*)(&tile[r * HIDDEN + q * 4]);
    }
}

// ---------------------------------------------------------------------------
// Overflow fixup: statistically zero entries; global fp32 atomics into out.
// ---------------------------------------------------------------------------
__global__ __launch_bounds__(256) void overflow_fix_kernel(
    const int* __restrict__ ovcnt, const int4* __restrict__ ovbuf,
    const unsigned int* __restrict__ support_u32, float* __restrict__ out)
{
    const int n    = min(*ovcnt, OV_CAP);
    const int wave = threadIdx.x >> 6;
    const int lane = threadIdx.x & 63;
    for (int j = wave; j < n; j += 4) {
        int4 o = ovbuf[j];
        unsigned u = support_u32[(size_t)o.y * 64 + lane];
        float v = __int_as_float(o.z);
        unsafeAtomicAdd(out + (size_t)o.x * HIDDEN + lane * 2,     v * bfLo(u));
        unsafeAtomicAdd(out + (size_t)o.x * HIDDEN + lane * 2 + 1, v * bfHi(u));
    }
}

extern "C" void kernel_launch(void* const* d_in, const int* in_sizes, int n_in,
                              void* d_out, int out_size, void* d_ws, size_t ws_size,
                              hipStream_t stream) {
    const float* x       = (const float*)d_in[0];
    const int*   adj_row = (const int*)d_in[1];
    const int*   adj_col = (const int*)d_in[2];
    const float* adj_val = (const float*)d_in[3];
    const float* W       = (const float*)d_in[4];
    const float* b       = (const float*)d_in[5];
    float* out = (float*)d_out;

    char* wsb = (char*)d_ws;
    const size_t off_support = 0;                                         // 12.8 MB bf16
    const size_t off_part    = off_support + (size_t)N_NODES * HIDDEN * 2;
    const size_t off_cursor  = off_part + (size_t)NB * CAP * 8;           // 8.4 MB
    const size_t off_ovcnt   = off_cursor + (size_t)NB * 4;
    const size_t off_ovbuf   = (off_ovcnt + 4 + 15) & ~(size_t)15;

    unsigned short* support = (unsigned short*)(wsb + off_support);
    int2* part   = (int2*)(wsb + off_part);
    int*  cursor = (int*)(wsb + off_cursor);
    int*  ovcnt  = (int*)(wsb + off_ovcnt);
    int4* ovbuf  = (int4*)(wsb + off_ovbuf);

    // zero cursor + ovcnt (contiguous)
    hipMemsetAsync(cursor, 0, (size_t)(NB + 1) * 4, stream);

    linear_mfma_kernel<<<(N_NODES + 63) / 64, 256, 0, stream>>>(x, W, b, support);
    partition_kernel<<<EBLOCKS, 256, 0, stream>>>(
        adj_row, adj_col, adj_val, cursor, part, ovbuf, ovcnt);
    bucket_gather_kernel<<<NB, 256, 0, stream>>>(
        cursor, part, (const unsigned int*)support, out);
    overflow_fix_kernel<<<1, 256, 0, stream>>>(
        ovcnt, ovbuf, (const unsigned int*)support, out);
}

// Round 7
// 192.775 us; speedup vs baseline: 4.2627x; 4.2627x over previous
//
#include <hip/hip_runtime.h>

#define N_NODES 50000
#define N_EDGES 800000
#define IN_F    256
#define HIDDEN  128

#define BUCKET_SZ 64                      // rows per bucket
#define NB        782                     // ceil(N_NODES / 64)
#define NBP       1024                    // padded scan width (4 per thread x 256)
#define EBLOCK    2048                    // edges per partition block
#define EBLOCKS   391                     // ceil(N_EDGES / EBLOCK)
#define CAP       1344                    // bucket region capacity (mean 1023, +10 sigma)
#define OV_CAP    4096                    // overflow list capacity

typedef __attribute__((ext_vector_type(8))) short bf16x8;
typedef __attribute__((ext_vector_type(4))) float f32x4;

__device__ inline unsigned short f2bf(float f) {
    unsigned u = __float_as_uint(f);
    u += 0x7FFF + ((u >> 16) & 1);          // round-to-nearest-even
    return (unsigned short)(u >> 16);
}
__device__ inline bf16x8 cvt8(float4 a, float4 b) {
    bf16x8 r;
    r[0] = (short)f2bf(a.x); r[1] = (short)f2bf(a.y);
    r[2] = (short)f2bf(a.z); r[3] = (short)f2bf(a.w);
    r[4] = (short)f2bf(b.x); r[5] = (short)f2bf(b.y);
    r[6] = (short)f2bf(b.z); r[7] = (short)f2bf(b.w);
    return r;
}
__device__ inline float bfLo(unsigned u) { return __uint_as_float(u << 16); }
__device__ inline float bfHi(unsigned u) { return __uint_as_float(u & 0xFFFF0000u); }

// ---------------------------------------------------------------------------
// Linear via MFMA bf16 (verified R4/R5): W staged once per block in LDS,
// pre-swizzled into B-fragment order; A-frags via coalesced global loads.
// ---------------------------------------------------------------------------
__global__ __launch_bounds__(256) void linear_mfma_kernel(
    const float* __restrict__ x, const float* __restrict__ W,
    const float* __restrict__ bias, unsigned short* __restrict__ support)
{
    __shared__ __align__(16) short wfrag[8 * 8 * 64 * 8];   // 64 KB

    const int tid = threadIdx.x;
#pragma unroll
    for (int it = 0; it < 16; ++it) {
        const int f    = it * 256 + tid;
        const int ln   = f & 63;
        const int s    = (f >> 6) & 7;
        const int kc   = f >> 9;
        const int row  = s * 16 + (ln & 15);
        const int k0   = kc * 32 + (ln >> 4) * 8;
        const float* wp = W + (size_t)row * IN_F + k0;
        float4 b0 = *(const float4*)wp;
        float4 b1 = *(const float4*)(wp + 4);
        *(bf16x8*)(&wfrag[(size_t)f * 8]) = cvt8(b0, b1);
    }
    __syncthreads();

    const int lane = tid & 63;
    const int wave = tid >> 6;
    const int quad = lane >> 4;
    const int l16  = lane & 15;

    int m = blockIdx.x * 64 + wave * 16 + l16;
    if (m >= N_NODES) m = N_NODES - 1;
    const float* xrow = x + (size_t)m * IN_F;

    f32x4 acc[8];
#pragma unroll
    for (int s = 0; s < 8; ++s) acc[s] = (f32x4){0.f, 0.f, 0.f, 0.f};

#pragma unroll
    for (int kc = 0; kc < 8; ++kc) {
        const int k0 = kc * 32 + quad * 8;
        float4 a0 = *(const float4*)(xrow + k0);
        float4 a1 = *(const float4*)(xrow + k0 + 4);
        bf16x8 af = cvt8(a0, a1);
        const short* bbase = &wfrag[((size_t)(kc * 8) * 64 + lane) * 8];
#pragma unroll
        for (int s = 0; s < 8; ++s) {
            bf16x8 bf = *(const bf16x8*)(bbase + (size_t)s * 64 * 8);
            acc[s] = __builtin_amdgcn_mfma_f32_16x16x32_bf16(af, bf, acc[s], 0, 0, 0);
        }
    }

    const int rowBase = blockIdx.x * 64 + wave * 16 + quad * 4;
#pragma unroll
    for (int reg = 0; reg < 4; ++reg) {
        const int r = rowBase + reg;
        if (r < N_NODES) {
#pragma unroll
            for (int s = 0; s < 8; ++s) {
                const int col = s * 16 + l16;
                float v = acc[s][reg] + bias[col];
                support[(size_t)r * HIDDEN + col] = f2bf(v);
            }
        }
    }
}

// ---------------------------------------------------------------------------
// Partition (verified R6): group each block's 2048 edges by bucket (row>>6)
// in LDS, reserve per-bucket space with ONE global atomicAdd per touched
// bucket, write bucket-contiguous runs into regions part[b*CAP ..].
// Entry in part: .x = (rowLocal<<16)|col   .y = val bits.
// ---------------------------------------------------------------------------
__global__ __launch_bounds__(256) void partition_kernel(
    const int* __restrict__ adj_row, const int* __restrict__ adj_col,
    const float* __restrict__ adj_val, int* __restrict__ cursor,
    int2* __restrict__ part, int4* __restrict__ ovbuf, int* __restrict__ ovcnt)
{
    __shared__ int  lcnt[NBP];     // counts, then exclusive offsets
    __shared__ int  lcur[NBP];
    __shared__ int  gbase[NBP];
    __shared__ int  tsum[256];
    __shared__ int2 lbuf[EBLOCK];  // 16 KB

    const int tid  = threadIdx.x;
    const int base = blockIdx.x * EBLOCK;
    const int n    = min(EBLOCK, N_EDGES - base);

    for (int i = tid; i < NBP; i += 256) lcnt[i] = 0;
    __syncthreads();

    unsigned pk[8]; float pv[8];
#pragma unroll
    for (int i = 0; i < 8; ++i) {
        int e = base + tid + i * 256;
        bool ok = e < N_EDGES;
        int ee = ok ? e : 0;
        int r = adj_row[ee], c = adj_col[ee];
        float v = adj_val[ee];
        if (ok) {
            unsigned bk = (unsigned)r >> 6;
            pk[i] = (bk << 22) | (((unsigned)r & 63u) << 16) | (unsigned)c;
            pv[i] = v;
            atomicAdd(&lcnt[bk], 1);
        } else pk[i] = 0xFFFFFFFFu;
    }
    __syncthreads();

    // exclusive scan of lcnt[0..1024): 4 per thread + Hillis-Steele over 256
    int s0 = lcnt[tid * 4], s1 = lcnt[tid * 4 + 1];
    int s2 = lcnt[tid * 4 + 2], s3 = lcnt[tid * 4 + 3];
    int mysum = s0 + s1 + s2 + s3;
    tsum[tid] = mysum;
    __syncthreads();
#pragma unroll
    for (int off = 1; off < 256; off <<= 1) {
        int t = (tid >= off) ? tsum[tid - off] : 0;
        __syncthreads();
        tsum[tid] += t;
        __syncthreads();
    }
    int ex = tsum[tid] - mysum;
    lcnt[tid * 4]     = ex;
    lcnt[tid * 4 + 1] = ex + s0;
    lcnt[tid * 4 + 2] = ex + s0 + s1;
    lcnt[tid * 4 + 3] = ex + s0 + s1 + s2;
    __syncthreads();

    // reserve global space per touched bucket; init cursors
    for (int b = tid; b < NB; b += 256) {
        int c = lcnt[b + 1] - lcnt[b];
        gbase[b] = (c > 0) ? atomicAdd(&cursor[b], c) : 0;
        lcur[b]  = lcnt[b];
    }
    __syncthreads();

    // group into lbuf
#pragma unroll
    for (int i = 0; i < 8; ++i) {
        if (pk[i] != 0xFFFFFFFFu) {
            unsigned bk = pk[i] >> 22;
            int p = atomicAdd(&lcur[bk], 1);
            lbuf[p] = make_int2((int)pk[i], __float_as_int(pv[i]));
        }
    }
    __syncthreads();

    // write bucket-contiguous runs
    for (int j = tid; j < n; j += 256) {
        int2 cv = lbuf[j];
        unsigned bk = ((unsigned)cv.x) >> 22;
        int loc = gbase[bk] + (j - lcnt[bk]);
        if (loc < CAP) {
            part[(size_t)bk * CAP + loc] = make_int2(cv.x & 0x3FFFFF, cv.y);
        } else {
            int op = atomicAdd(ovcnt, 1);
            if (op < OV_CAP) {
                int r = (int)(bk * BUCKET_SZ) + ((cv.x >> 16) & 63);
                ovbuf[op] = make_int4(r, cv.x & 0xFFFF, cv.y, 0);
            }
        }
    }
}

// ---------------------------------------------------------------------------
// Bucket gather v2 (NO fp32 atomics): load bucket entries into registers,
// in-LDS 64-bin row sort (int ops only), then wave w owns rows [16w,16w+16):
// per row, ds_read entries (same-addr broadcast), coalesced 256 B support
// gather, register accumulate, direct float2 store to out.
// ---------------------------------------------------------------------------
__global__ __launch_bounds__(256) void bucket_gather_kernel(
    const int* __restrict__ cursor, const int2* __restrict__ part,
    const unsigned int* __restrict__ support_u32, float* __restrict__ out)
{
    __shared__ int2 sbuf[CAP];            // row-sorted entries, 10.5 KB
    __shared__ int  hist[BUCKET_SZ];
    __shared__ int  rp[BUCKET_SZ + 1];    // row_ptr within bucket
    __shared__ int  cur[BUCKET_SZ];

    const int tid  = threadIdx.x;
    const int b    = blockIdx.x;
    const int n    = min(cursor[b], CAP);
    const int wave = tid >> 6;
    const int lane = tid & 63;

    if (tid < BUCKET_SZ) hist[tid] = 0;
    __syncthreads();

    // load entries (coalesced) + histogram
    int2 held[(CAP + 255) / 256];
    int  nheld = 0;
    const int2* pb = part + (size_t)b * CAP;
    for (int j = tid; j < n; j += 256) {
        int2 cv = pb[j];
        held[nheld++] = cv;
        atomicAdd(&hist[(cv.x >> 16) & 63], 1);
    }
    __syncthreads();

    // wave 0: 64-wide shuffle scan -> row_ptr + cursors
    if (tid < 64) {
        int v = hist[tid];
        int incl = v;
#pragma unroll
        for (int off = 1; off < 64; off <<= 1) {
            int t = __shfl_up(incl, off);
            if (tid >= off) incl += t;
        }
        rp[tid + 1] = incl;
        if (tid == 0) rp[0] = 0;
        cur[tid] = incl - v;
    }
    __syncthreads();

    // place row-sorted
    for (int i = 0; i < nheld; ++i) {
        int r = (held[i].x >> 16) & 63;
        int p = atomicAdd(&cur[r], 1);
        sbuf[p] = held[i];
    }
    __syncthreads();

    // wave phase: disjoint rows per wave -> no races
    const int rowLo = wave * 16;
#pragma unroll 1
    for (int r = rowLo; r < rowLo + 16; ++r) {
        const int grow = b * BUCKET_SZ + r;
        if (grow >= N_NODES) break;
        const int s = rp[r], e = rp[r + 1];
        float ax = 0.f, ay = 0.f;
        int j = s;
        for (; j + 3 < e; j += 4) {
            int2 c0 = sbuf[j],     c1 = sbuf[j + 1];
            int2 c2 = sbuf[j + 2], c3 = sbuf[j + 3];
            unsigned u0 = support_u32[(size_t)(c0.x & 0xFFFF) * 64 + lane];
            unsigned u1 = support_u32[(size_t)(c1.x & 0xFFFF) * 64 + lane];
            unsigned u2 = support_u32[(size_t)(c2.x & 0xFFFF) * 64 + lane];
            unsigned u3 = support_u32[(size_t)(c3.x & 0xFFFF) * 64 + lane];
            float v0 = __int_as_float(c0.y), v1 = __int_as_float(c1.y);
            float v2 = __int_as_float(c2.y), v3 = __int_as_float(c3.y);
            ax += v0 * bfLo(u0); ay += v0 * bfHi(u0);
            ax += v1 * bfLo(u1); ay += v1 * bfHi(u1);
            ax += v2 * bfLo(u2); ay += v2 * bfHi(u2);
            ax += v3 * bfLo(u3); ay += v3 * bfHi(u3);
        }
        for (; j < e; ++j) {
            int2 cv = sbuf[j];
            unsigned u = support_u32[(size_t)(cv.x & 0xFFFF) * 64 + lane];
            float v = __int_as_float(cv.y);
            ax += v * bfLo(u); ay += v * bfHi(u);
        }
        *(float2*)(out + (size_t)grow * HIDDEN + lane * 2) = make_float2(ax, ay);
    }
}

// ---------------------------------------------------------------------------
// Overflow fixup (statistically empty); runs after bucket_gather in-stream.
// ---------------------------------------------------------------------------
__global__ __launch_bounds__(256) void overflow_fix_kernel(
    const int* __restrict__ ovcnt, const int4* __restrict__ ovbuf,
    const unsigned int* __restrict__ support_u32, float* __restrict__ out)
{
    const int n    = min(*ovcnt, OV_CAP);
    const int wave = threadIdx.x >> 6;
    const int lane = threadIdx.x & 63;
    for (int j = wave; j < n; j += 4) {
        int4 o = ovbuf[j];
        unsigned u = support_u32[(size_t)o.y * 64 + lane];
        float v = __int_as_float(o.z);
        unsafeAtomicAdd(out + (size_t)o.x * HIDDEN + lane * 2,     v * bfLo(u));
        unsafeAtomicAdd(out + (size_t)o.x * HIDDEN + lane * 2 + 1, v * bfHi(u));
    }
}

extern "C" void kernel_launch(void* const* d_in, const int* in_sizes, int n_in,
                              void* d_out, int out_size, void* d_ws, size_t ws_size,
                              hipStream_t stream) {
    const float* x       = (const float*)d_in[0];
    const int*   adj_row = (const int*)d_in[1];
    const int*   adj_col = (const int*)d_in[2];
    const float* adj_val = (const float*)d_in[3];
    const float* W       = (const float*)d_in[4];
    const float* b       = (const float*)d_in[5];
    float* out = (float*)d_out;

    char* wsb = (char*)d_ws;
    const size_t off_support = 0;                                         // 12.8 MB bf16
    const size_t off_part    = off_support + (size_t)N_NODES * HIDDEN * 2;
    const size_t off_cursor  = off_part + (size_t)NB * CAP * 8;           // 8.4 MB
    const size_t off_ovcnt   = off_cursor + (size_t)NB * 4;
    const size_t off_ovbuf   = (off_ovcnt + 4 + 15) & ~(size_t)15;

    unsigned short* support = (unsigned short*)(wsb + off_support);
    int2* part   = (int2*)(wsb + off_part);
    int*  cursor = (int*)(wsb + off_cursor);
    int*  ovcnt  = (int*)(wsb + off_ovcnt);
    int4* ovbuf  = (int4*)(wsb + off_ovbuf);

    // zero cursor + ovcnt (contiguous)
    hipMemsetAsync(cursor, 0, (size_t)(NB + 1) * 4, stream);

    linear_mfma_kernel<<<(N_NODES + 63) / 64, 256, 0, stream>>>(x, W, b, support);
    partition_kernel<<<EBLOCKS, 256, 0, stream>>>(
        adj_row, adj_col, adj_val, cursor, part, ovbuf, ovcnt);
    bucket_gather_kernel<<<NB, 256, 0, stream>>>(
        cursor, part, (const unsigned int*)support, out);
    overflow_fix_kernel<<<1, 256, 0, stream>>>(
        ovcnt, ovbuf, (const unsigned int*)support, out);
}

// Round 8
// 186.964 us; speedup vs baseline: 4.3952x; 1.0311x over previous
//
#include <hip/hip_runtime.h>

#define N_NODES 50000
#define N_EDGES 800000
#define IN_F    256
#define HIDDEN  128

#define BUCKET_SZ 128                     // rows per bucket
#define NB        391                     // ceil(N_NODES / 128)
#define NBS       512                     // padded scan width (2 per thread x 256)
#define EBLOCK    2048                    // edges per partition block
#define EBLOCKS   391                     // ceil(N_EDGES / EBLOCK)
#define LBLOCKS   782                     // linear blocks (64 rows each)
#define CAP       2500                    // bucket capacity (mean 2046, +10 sigma)
#define OV_CAP    4096                    // overflow list capacity

typedef __attribute__((ext_vector_type(8))) short bf16x8;
typedef __attribute__((ext_vector_type(4))) float f32x4;

__device__ inline unsigned short f2bf(float f) {
    unsigned u = __float_as_uint(f);
    u += 0x7FFF + ((u >> 16) & 1);          // round-to-nearest-even
    return (unsigned short)(u >> 16);
}
__device__ inline bf16x8 cvt8(float4 a, float4 b) {
    bf16x8 r;
    r[0] = (short)f2bf(a.x); r[1] = (short)f2bf(a.y);
    r[2] = (short)f2bf(a.z); r[3] = (short)f2bf(a.w);
    r[4] = (short)f2bf(b.x); r[5] = (short)f2bf(b.y);
    r[6] = (short)f2bf(b.z); r[7] = (short)f2bf(b.w);
    return r;
}
__device__ inline float bfLo(unsigned u) { return __uint_as_float(u << 16); }
__device__ inline float bfHi(unsigned u) { return __uint_as_float(u & 0xFFFF0000u); }

// ---------------------------------------------------------------------------
// Fused linear (MFMA bf16) + edge partition. Blocks [0, EBLOCKS) partition;
// blocks [EBLOCKS, EBLOCKS+LBLOCKS) compute support. Independent inputs, so
// co-scheduling overlaps the MFMA pipe with the memory/LDS pipe.
// Shared LDS: 32 KB union (linear stages W in 2 halves of 4 k-chunks).
// ---------------------------------------------------------------------------
__global__ __launch_bounds__(256) void fused_linear_partition_kernel(
    const float* __restrict__ x, const float* __restrict__ W,
    const float* __restrict__ bias, unsigned short* __restrict__ support,
    const int* __restrict__ adj_row, const int* __restrict__ adj_col,
    const float* __restrict__ adj_val, int* __restrict__ cursor,
    int2* __restrict__ part, int4* __restrict__ ovbuf, int* __restrict__ ovcnt)
{
    __shared__ __align__(16) char smem[32768];
    const int tid = threadIdx.x;

    if (blockIdx.x < EBLOCKS) {
        // ================= PARTITION branch =================
        int2* lbuf  = (int2*)smem;                    // 16384 B
        int*  lofs  = (int*)(smem + 16384);           // 2048 B (counts -> excl offsets)
        int*  lcur  = (int*)(smem + 18432);           // 2048 B
        int*  gbase = (int*)(smem + 20480);           // 2048 B
        int*  tsum  = (int*)(smem + 22528);           // 1024 B

        const int base = blockIdx.x * EBLOCK;
        const int n    = min(EBLOCK, N_EDGES - base);

        for (int i = tid; i < NBS; i += 256) lofs[i] = 0;
        __syncthreads();

        unsigned pk[8]; float pv[8];
#pragma unroll
        for (int i = 0; i < 8; ++i) {
            int e = base + tid + i * 256;
            bool ok = e < N_EDGES;
            int ee = ok ? e : 0;
            int r = adj_row[ee], c = adj_col[ee];
            float v = adj_val[ee];
            if (ok) {
                unsigned bk = (unsigned)r >> 7;
                pk[i] = (bk << 23) | (((unsigned)r & 127u) << 16) | (unsigned)c;
                pv[i] = v;
                atomicAdd(&lofs[bk], 1);
            } else pk[i] = 0xFFFFFFFFu;
        }
        __syncthreads();

        // exclusive scan over 512 bins: 2 per thread + Hillis-Steele over 256
        int s0 = lofs[tid * 2], s1 = lofs[tid * 2 + 1];
        int mysum = s0 + s1;
        tsum[tid] = mysum;
        __syncthreads();
#pragma unroll
        for (int off = 1; off < 256; off <<= 1) {
            int t = (tid >= off) ? tsum[tid - off] : 0;
            __syncthreads();
            tsum[tid] += t;
            __syncthreads();
        }
        int ex = tsum[tid] - mysum;
        lofs[tid * 2]     = ex;
        lofs[tid * 2 + 1] = ex + s0;
        __syncthreads();

        // reserve global space per touched bucket; init cursors
        for (int b = tid; b < NB; b += 256) {
            int nb2 = (b * 2 + 2 < NBS) ? lofs[b + 1] : n;   // lofs[b+1] valid (NBS pad)
            int c = lofs[b + 1] - lofs[b];
            (void)nb2;
            gbase[b] = (c > 0) ? atomicAdd(&cursor[b], c) : 0;
            lcur[b]  = lofs[b];
        }
        __syncthreads();

        // group into lbuf (bucket-contiguous)
#pragma unroll
        for (int i = 0; i < 8; ++i) {
            if (pk[i] != 0xFFFFFFFFu) {
                unsigned bk = pk[i] >> 23;
                int p = atomicAdd(&lcur[bk], 1);
                lbuf[p] = make_int2((int)pk[i], __float_as_int(pv[i]));
            }
        }
        __syncthreads();

        // write bucket-contiguous runs
        for (int j = tid; j < n; j += 256) {
            int2 cv = lbuf[j];
            unsigned bk = ((unsigned)cv.x) >> 23;
            int loc = gbase[bk] + (j - lofs[bk]);
            if (loc < CAP) {
                part[(size_t)bk * CAP + loc] = make_int2(cv.x & 0x7FFFFF, cv.y);
            } else {
                int op = atomicAdd(ovcnt, 1);
                if (op < OV_CAP) {
                    int r = (int)(bk * BUCKET_SZ) + ((cv.x >> 16) & 127);
                    ovbuf[op] = make_int4(r, cv.x & 0xFFFF, cv.y, 0);
                }
            }
        }
    } else {
        // ================= LINEAR branch =================
        short* wfrag = (short*)smem;                  // 32 KB: 4 kc x 8 strips x 64 lanes x 8

        const int bid  = blockIdx.x - EBLOCKS;
        const int lane = tid & 63;
        const int wave = tid >> 6;
        const int quad = lane >> 4;
        const int l16  = lane & 15;

        int m = bid * 64 + wave * 16 + l16;
        if (m >= N_NODES) m = N_NODES - 1;
        const float* xrow = x + (size_t)m * IN_F;

        f32x4 acc[8];
#pragma unroll
        for (int s = 0; s < 8; ++s) acc[s] = (f32x4){0.f, 0.f, 0.f, 0.f};

#pragma unroll
        for (int half = 0; half < 2; ++half) {
            // stage 4 k-chunks of W fragments (2048 frags of 16 B, 8/thread)
#pragma unroll
            for (int it = 0; it < 8; ++it) {
                const int f   = it * 256 + tid;
                const int ln  = f & 63;
                const int s   = (f >> 6) & 7;
                const int kc  = f >> 9;               // 0..3
                const int row = s * 16 + (ln & 15);
                const int k0  = (half * 4 + kc) * 32 + (ln >> 4) * 8;
                const float* wp = W + (size_t)row * IN_F + k0;
                float4 b0 = *(const float4*)wp;
                float4 b1 = *(const float4*)(wp + 4);
                *(bf16x8*)(&wfrag[(size_t)f * 8]) = cvt8(b0, b1);
            }
            __syncthreads();

#pragma unroll
            for (int kc = 0; kc < 4; ++kc) {
                const int k0 = (half * 4 + kc) * 32 + quad * 8;
                float4 a0 = *(const float4*)(xrow + k0);
                float4 a1 = *(const float4*)(xrow + k0 + 4);
                bf16x8 af = cvt8(a0, a1);
                const short* bbase = &wfrag[((size_t)(kc * 8) * 64 + lane) * 8];
#pragma unroll
                for (int s = 0; s < 8; ++s) {
                    bf16x8 bf = *(const bf16x8*)(bbase + (size_t)s * 64 * 8);
                    acc[s] = __builtin_amdgcn_mfma_f32_16x16x32_bf16(af, bf, acc[s], 0, 0, 0);
                }
            }
            __syncthreads();
        }

        const int rowBase = bid * 64 + wave * 16 + quad * 4;
#pragma unroll
        for (int reg = 0; reg < 4; ++reg) {
            const int r = rowBase + reg;
            if (r < N_NODES) {
#pragma unroll
                for (int s = 0; s < 8; ++s) {
                    const int col = s * 16 + l16;
                    float v = acc[s][reg] + bias[col];
                    support[(size_t)r * HIDDEN + col] = f2bf(v);
                }
            }
        }
    }
}

// ---------------------------------------------------------------------------
// Bucket gather (no fp32 atomics): 512 threads = 8 waves per 128-row bucket.
// Load entries, LDS 128-bin row sort (int ops only), wave w owns rows
// [16w,16w+16): ds_read entry (broadcast), coalesced 256 B support gather,
// register accumulate, direct float2 store.
// ---------------------------------------------------------------------------
__global__ __launch_bounds__(512) void bucket_gather_kernel(
    const int* __restrict__ cursor, const int2* __restrict__ part,
    const unsigned int* __restrict__ support_u32, float* __restrict__ out)
{
    __shared__ int2 sbuf[CAP];                // 20 KB
    __shared__ int  hist[BUCKET_SZ];
    __shared__ int  rp[BUCKET_SZ + 1];
    __shared__ int  cur[BUCKET_SZ];

    const int tid  = threadIdx.x;
    const int b    = blockIdx.x;
    const int n    = min(cursor[b], CAP);
    const int wave = tid >> 6;
    const int lane = tid & 63;

    if (tid < BUCKET_SZ) hist[tid] = 0;
    __syncthreads();

    // load entries (coalesced) + histogram
    int2 held[(CAP + 511) / 512];
    int  nheld = 0;
    const int2* pb = part + (size_t)b * CAP;
    for (int j = tid; j < n; j += 512) {
        int2 cv = pb[j];
        held[nheld++] = cv;
        atomicAdd(&hist[(cv.x >> 16) & 127], 1);
    }
    __syncthreads();

    // wave 0: scan 128 bins via two 64-wide shuffle scans
    if (tid < 64) {
        int a = hist[tid], c = hist[tid + 64];
        int ia = a, ic = c;
#pragma unroll
        for (int off = 1; off < 64; off <<= 1) {
            int ta = __shfl_up(ia, off);
            int tc = __shfl_up(ic, off);
            if (tid >= off) { ia += ta; ic += tc; }
        }
        int totA = __shfl(ia, 63);
        rp[tid + 1]      = ia;
        rp[tid + 65]     = totA + ic;
        if (tid == 0) rp[0] = 0;
        cur[tid]      = ia - a;
        cur[tid + 64] = totA + ic - c;
    }
    __syncthreads();

    // place row-sorted
    for (int i = 0; i < nheld; ++i) {
        int r = (held[i].x >> 16) & 127;
        int p = atomicAdd(&cur[r], 1);
        sbuf[p] = held[i];
    }
    __syncthreads();

    // wave phase: disjoint rows per wave -> no races
    const int rowLo = wave * 16;
#pragma unroll 1
    for (int r = rowLo; r < rowLo + 16; ++r) {
        const int grow = b * BUCKET_SZ + r;
        if (grow >= N_NODES) break;
        const int s = rp[r], e = rp[r + 1];
        float ax = 0.f, ay = 0.f;
        int j = s;
        for (; j + 3 < e; j += 4) {
            int2 c0 = sbuf[j],     c1 = sbuf[j + 1];
            int2 c2 = sbuf[j + 2], c3 = sbuf[j + 3];
            unsigned u0 = support_u32[(size_t)(c0.x & 0xFFFF) * 64 + lane];
            unsigned u1 = support_u32[(size_t)(c1.x & 0xFFFF) * 64 + lane];
            unsigned u2 = support_u32[(size_t)(c2.x & 0xFFFF) * 64 + lane];
            unsigned u3 = support_u32[(size_t)(c3.x & 0xFFFF) * 64 + lane];
            float v0 = __int_as_float(c0.y), v1 = __int_as_float(c1.y);
            float v2 = __int_as_float(c2.y), v3 = __int_as_float(c3.y);
            ax += v0 * bfLo(u0); ay += v0 * bfHi(u0);
            ax += v1 * bfLo(u1); ay += v1 * bfHi(u1);
            ax += v2 * bfLo(u2); ay += v2 * bfHi(u2);
            ax += v3 * bfLo(u3); ay += v3 * bfHi(u3);
        }
        for (; j < e; ++j) {
            int2 cv = sbuf[j];
            unsigned u = support_u32[(size_t)(cv.x & 0xFFFF) * 64 + lane];
            float v = __int_as_float(cv.y);
            ax += v * bfLo(u); ay += v * bfHi(u);
        }
        *(float2*)(out + (size_t)grow * HIDDEN + lane * 2) = make_float2(ax, ay);
    }
}

// ---------------------------------------------------------------------------
// Overflow fixup (statistically empty).
// ---------------------------------------------------------------------------
__global__ __launch_bounds__(256) void overflow_fix_kernel(
    const int* __restrict__ ovcnt, const int4* __restrict__ ovbuf,
    const unsigned int* __restrict__ support_u32, float* __restrict__ out)
{
    const int n    = min(*ovcnt, OV_CAP);
    const int wave = threadIdx.x >> 6;
    const int lane = threadIdx.x & 63;
    for (int j = wave; j < n; j += 4) {
        int4 o = ovbuf[j];
        unsigned u = support_u32[(size_t)o.y * 64 + lane];
        float v = __int_as_float(o.z);
        unsafeAtomicAdd(out + (size_t)o.x * HIDDEN + lane * 2,     v * bfLo(u));
        unsafeAtomicAdd(out + (size_t)o.x * HIDDEN + lane * 2 + 1, v * bfHi(u));
    }
}

extern "C" void kernel_launch(void* const* d_in, const int* in_sizes, int n_in,
                              void* d_out, int out_size, void* d_ws, size_t ws_size,
                              hipStream_t stream) {
    const float* x       = (const float*)d_in[0];
    const int*   adj_row = (const int*)d_in[1];
    const int*   adj_col = (const int*)d_in[2];
    const float* adj_val = (const float*)d_in[3];
    const float* W       = (const float*)d_in[4];
    const float* b       = (const float*)d_in[5];
    float* out = (float*)d_out;

    char* wsb = (char*)d_ws;
    const size_t off_support = 0;                                         // 12.8 MB bf16
    const size_t off_part    = off_support + (size_t)N_NODES * HIDDEN * 2;
    const size_t off_cursor  = off_part + (size_t)NB * CAP * 8;           // 7.8 MB
    const size_t off_ovcnt   = off_cursor + (size_t)NB * 4;
    const size_t off_ovbuf   = (off_ovcnt + 4 + 15) & ~(size_t)15;

    unsigned short* support = (unsigned short*)(wsb + off_support);
    int2* part   = (int2*)(wsb + off_part);
    int*  cursor = (int*)(wsb + off_cursor);
    int*  ovcnt  = (int*)(wsb + off_ovcnt);
    int4* ovbuf  = (int4*)(wsb + off_ovbuf);

    // zero cursor + ovcnt (contiguous)
    hipMemsetAsync(cursor, 0, (size_t)(NB + 1) * 4, stream);

    fused_linear_partition_kernel<<<EBLOCKS + LBLOCKS, 256, 0, stream>>>(
        x, W, b, support, adj_row, adj_col, adj_val, cursor, part, ovbuf, ovcnt);
    bucket_gather_kernel<<<NB, 512, 0, stream>>>(
        cursor, part, (const unsigned int*)support, out);
    overflow_fix_kernel<<<1, 256, 0, stream>>>(
        ovcnt, ovbuf, (const unsigned int*)support, out);
}